// Round 9
// baseline (503.201 us; speedup 1.0000x reference)
//
#include <hip/hip_runtime.h>

#define N_NODES 50000
#define MP 50048            // row-tile padding (128-multiple) for GEMM grids

typedef short short8 __attribute__((ext_vector_type(8)));
typedef float floatx4 __attribute__((ext_vector_type(4)));
typedef ushort u16x8 __attribute__((ext_vector_type(8)));
typedef float f32x4 __attribute__((ext_vector_type(4)));

__device__ __forceinline__ float bf2f(ushort u) {
    union { unsigned int i; float f; } x; x.i = ((unsigned int)u) << 16; return x.f;
}
__device__ __forceinline__ ushort f2bf(float f) {
    union { float f; unsigned int i; } x; x.f = f;
    unsigned int r = x.i + 0x7FFFu + ((x.i >> 16) & 1u);
    return (ushort)(r >> 16);
}

// ---------- CSR build ----------
__global__ __launch_bounds__(256) void deg_int_kernel(const int* __restrict__ dst,
                                                      int* __restrict__ deg, int E) {
    int i = blockIdx.x * 256 + threadIdx.x;
    if (i < E) atomicAdd(&deg[dst[i]], 1);
}
__global__ __launch_bounds__(256) void inv_from_deg(const int* __restrict__ deg,
                                                    float* __restrict__ inv, int n) {
    int i = blockIdx.x * 256 + threadIdx.x;
    if (i < n) inv[i] = rsqrtf((float)deg[i] + 1.0f);
}

// ---- hierarchical exclusive scan (n <= 256*256) ----
__global__ __launch_bounds__(256) void scan1_kernel(const int* __restrict__ deg,
                                                    int* __restrict__ pre,
                                                    int* __restrict__ bsum, int n) {
    __shared__ int tmp[256];
    const int t = threadIdx.x;
    const int i = blockIdx.x * 256 + t;
    const int v = (i < n) ? deg[i] : 0;
    tmp[t] = v;
    __syncthreads();
#pragma unroll
    for (int d = 1; d < 256; d <<= 1) {
        int u = (t >= d) ? tmp[t - d] : 0;
        __syncthreads();
        tmp[t] += u;
        __syncthreads();
    }
    if (i < n) pre[i] = tmp[t] - v;           // exclusive within block
    if (t == 255) bsum[blockIdx.x] = tmp[255];
}
__global__ __launch_bounds__(256) void scan2_kernel(int* __restrict__ bsum, int nb,
                                                    int* __restrict__ row_ptr_n) {
    __shared__ int tmp[256];
    const int t = threadIdx.x;
    const int v = (t < nb) ? bsum[t] : 0;
    tmp[t] = v;
    __syncthreads();
#pragma unroll
    for (int d = 1; d < 256; d <<= 1) {
        int u = (t >= d) ? tmp[t - d] : 0;
        __syncthreads();
        tmp[t] += u;
        __syncthreads();
    }
    if (t < nb) bsum[t] = tmp[t] - v;         // exclusive block offsets
    if (t == 255) *row_ptr_n = tmp[255];      // grand total
}
__global__ __launch_bounds__(256) void scan3_kernel(const int* __restrict__ pre,
                                                    const int* __restrict__ bsum,
                                                    int* __restrict__ row_ptr,
                                                    int* __restrict__ cursor, int n) {
    const int i = blockIdx.x * 256 + threadIdx.x;
    if (i < n) {
        int v = pre[i] + bsum[blockIdx.x];
        row_ptr[i] = v;
        cursor[i] = v;
    }
}
// fill interleaved adjacency: adjw[pos] = (src, bits(invs[src]))
__global__ __launch_bounds__(256) void fill_adj_kernel(const int* __restrict__ src,
                                                       const int* __restrict__ dst,
                                                       const float* __restrict__ invs,
                                                       int* __restrict__ cursor,
                                                       int2* __restrict__ adjw, int E) {
    int i = blockIdx.x * 256 + threadIdx.x;
    if (i < E) {
        int s = src[i];
        int pos = atomicAdd(&cursor[dst[i]], 1);
        adjw[pos] = make_int2(s, __float_as_int(invs[s]));
    }
}

// ---------- weight prep ----------
__global__ __launch_bounds__(256) void f2b_kernel(const float* __restrict__ in,
                                                  ushort* __restrict__ out, int n) {
    int i = blockIdx.x * 256 + threadIdx.x;
    if (i < n) out[i] = f2bf(in[i]);
}
__global__ __launch_bounds__(256) void transpose_kernel(const float* __restrict__ W,
                                                        ushort* __restrict__ Wt, int K, int N) {
    int idx = blockIdx.x * 256 + threadIdx.x;
    if (idx < K * N) {
        int k = idx / N, n = idx % N;
        Wt[n * K + k] = f2bf(W[idx]);
    }
}

// ---------- bf16 MFMA GEMM:  C[M,N] = A[M,K] @ Bt[N,K]^T ----------
// 128x128 tile, 8 waves (512 thr), wave = 64x32 quadrant -> 32 AGPR acc.
// grid = (N/128, M/128): column-tiles of the same row-tile dispatch adjacently (L3 reuse of A).
__global__ __launch_bounds__(512, 4) void gemm_kernel(
    const ushort* __restrict__ A, const ushort* __restrict__ Bt,
    ushort* __restrict__ C, const float* __restrict__ bias,
    int M, int K, int N, int do_relu)
{
    __shared__ __align__(16) ushort Alds[128 * 32];
    __shared__ __align__(16) ushort Blds[128 * 32];
    const int t = threadIdx.x;
    const int w = t >> 6, l = t & 63;
    const int m0 = blockIdx.y * 128;
    const int n0 = blockIdx.x * 128;
    const int wr = (w >> 2) * 64, wc = (w & 3) * 32;
    const int lhi = l >> 4, llo = l & 15;

    floatx4 acc[4][2] = {};

    // staging: one global_load_lds per wave per buffer; dest = base + w*1024B + l*16B (lane-linear)
    const int srow = w * 16 + (l >> 2);      // 0..127
    const int scol = (l & 3) * 8;            // ushort offset within row
    int gr = m0 + srow; gr = gr < M ? gr : M - 1;
    const ushort* gA = A + (size_t)gr * K + scol;
    const ushort* gB = Bt + (size_t)(n0 + srow) * K + scol;
    ushort* lA = Alds + srow * 32 + scol;
    ushort* lB = Blds + srow * 32 + scol;

    const int nkt = K >> 5;
    for (int kt = 0; kt < nkt; ++kt) {
        const int k0 = kt << 5;
        __builtin_amdgcn_global_load_lds(
            (const __attribute__((address_space(1))) void*)(gA + k0),
            (__attribute__((address_space(3))) void*)lA, 16, 0, 0);
        __builtin_amdgcn_global_load_lds(
            (const __attribute__((address_space(1))) void*)(gB + k0),
            (__attribute__((address_space(3))) void*)lB, 16, 0, 0);
        __syncthreads();
        short8 av[4], bv[2];
#pragma unroll
        for (int m = 0; m < 4; ++m)
            av[m] = *reinterpret_cast<const short8*>(&Alds[(wr + m * 16 + llo) * 32 + lhi * 8]);
#pragma unroll
        for (int n = 0; n < 2; ++n)
            bv[n] = *reinterpret_cast<const short8*>(&Blds[(wc + n * 16 + llo) * 32 + lhi * 8]);
#pragma unroll
        for (int m = 0; m < 4; ++m)
#pragma unroll
            for (int n = 0; n < 2; ++n)
                acc[m][n] = __builtin_amdgcn_mfma_f32_16x16x32_bf16(av[m], bv[n], acc[m][n], 0, 0, 0);
        __syncthreads();
    }

    const int lr = lhi * 4;
#pragma unroll
    for (int m = 0; m < 4; ++m) {
#pragma unroll
        for (int n = 0; n < 2; ++n) {
            int gcol = n0 + wc + n * 16 + llo;
            float badd = bias ? bias[gcol] : 0.0f;
#pragma unroll
            for (int j = 0; j < 4; ++j) {
                int grow = m0 + wr + m * 16 + lr + j;
                if (grow < M) {
                    float v = acc[m][n][j] + badd;
                    if (do_relu) v = fmaxf(v, 0.0f);
                    C[(size_t)grow * N + gcol] = f2bf(v);
                }
            }
        }
    }
}

// ---------- CSR gather + fused epilogue ----------
// One wave per TWO nodes: half-wave (32 lanes) per node, lane owns 8 consecutive
// channels (dwordx4 loads). Edge loop unrolled x4 per half -> 8 rows in flight/wave.
template<bool RELU, bool BIAS, bool WF, bool WB>
__global__ __launch_bounds__(256) void gather_kernel(
    const int* __restrict__ row_ptr, const int2* __restrict__ adjw,
    const ushort* __restrict__ h, int ldh,
    const float* __restrict__ invs, const float* __restrict__ bias,
    float* __restrict__ outF, ushort* __restrict__ outB, int ldo)
{
    const int wv = threadIdx.x >> 6, l = threadIdx.x & 63;
    const int half = l >> 5, j = l & 31;
    const int node = blockIdx.x * 8 + wv * 2 + half;
    const bool valid = node < N_NODES;
    const int nd = valid ? node : N_NODES - 1;
    const int c0 = blockIdx.y * 256 + j * 8;
    const int beg = row_ptr[nd], end = row_ptr[nd + 1];
    const float invd = invs[nd];
    const int deg = end - beg;
    const int dmax = max(deg, __shfl_xor(deg, 32));   // max degree over the wave's 2 nodes

    float a0[8] = {}, a1[8] = {};
    const int iters = (dmax + 3) >> 2;
    for (int it = 0; it < iters; ++it) {
        const int e = beg + it * 4;
#pragma unroll
        for (int u = 0; u < 4; ++u) {
            int ee = e + u;
            int ec = min(ee, end - 1); ec = max(ec, 0);          // clamp (deg-0 safe)
            const int2 aw = adjw[ec];
            const float w = (ee < end) ? __int_as_float(aw.y) * invd : 0.0f;
            const u16x8 hv = *reinterpret_cast<const u16x8*>(h + (unsigned)(aw.x * ldh + c0));
            if (u & 1) {
#pragma unroll
                for (int k = 0; k < 8; ++k) a1[k] += bf2f(hv[k]) * w;
            } else {
#pragma unroll
                for (int k = 0; k < 8; ++k) a0[k] += bf2f(hv[k]) * w;
            }
        }
    }
    {   // self-loop + merge
        const float ws = invd * invd;
        const u16x8 hs = *reinterpret_cast<const u16x8*>(h + (unsigned)(nd * ldh + c0));
#pragma unroll
        for (int k = 0; k < 8; ++k) a0[k] += a1[k] + bf2f(hs[k]) * ws;
    }
#pragma unroll
    for (int k = 0; k < 8; ++k) {
        float v = a0[k];
        if (BIAS) v += bias[c0 + k];
        if (RELU) v = fmaxf(v, 0.0f);
        a0[k] = v;
    }
    if (valid) {
        if (WF) {
            float* op = outF + (size_t)node * ldo + c0;
            *reinterpret_cast<f32x4*>(op)     = *reinterpret_cast<f32x4*>(&a0[0]);
            *reinterpret_cast<f32x4*>(op + 4) = *reinterpret_cast<f32x4*>(&a0[4]);
        }
        if (WB) {
            u16x8 o;
#pragma unroll
            for (int k = 0; k < 8; ++k) o[k] = f2bf(a0[k]);
            *reinterpret_cast<u16x8*>(outB + (size_t)node * ldo + c0) = o;
        }
    }
}

extern "C" void kernel_launch(void* const* d_in, const int* in_sizes, int n_in,
                              void* d_out, int out_size, void* d_ws, size_t ws_size,
                              hipStream_t stream)
{
    const float* x  = (const float*)d_in[0];
    const int* ei1  = (const int*)d_in[1];
    const int* ei2  = (const int*)d_in[2];
    const float* W1 = (const float*)d_in[3];
    const float* b1 = (const float*)d_in[4];
    const float* W2 = (const float*)d_in[5];
    const float* b2 = (const float*)d_in[6];
    const float* W3 = (const float*)d_in[7];
    const float* b3 = (const float*)d_in[8];
    const float* W4 = (const float*)d_in[9];
    const float* b4 = (const float*)d_in[10];
    float* z   = (float*)d_out;                        // [50000,256] f32
    float* z_g = z + (size_t)N_NODES * 256;            // [50000,256] f32

    const int E1 = in_sizes[1] / 2, E2 = in_sizes[2] / 2;
    const int* src1 = ei1;  const int* dst1 = ei1 + E1;
    const int* src2 = ei2;  const int* dst2 = ei2 + E2;

    // ---- aliases on d_out (each half = 51.2 MB = [50000,512] bf16 exactly) ----
    ushort* Xb = (ushort*)z;      // bf16 x; dead after GEMM1; then z f32 overwrites
    ushort* R1 = (ushort*)z_g;    // 512-wide bf16 ping buffer; final gather writes z_g f32 over it

    // ---- workspace (~61 MB) ----
    char* ws = (char*)d_ws;
    size_t off = 0;
    auto alloc = [&](size_t bytes) { void* p = ws + off; off += (bytes + 255) & ~(size_t)255; return p; };
    ushort* R0   = (ushort*)alloc((size_t)N_NODES * 512 * 2);
    float*  inv1 = (float*) alloc((size_t)N_NODES * 4);
    float*  inv2 = (float*) alloc((size_t)N_NODES * 4);
    int*    deg1 = (int*)   alloc((size_t)N_NODES * 4);
    int*    deg2 = (int*)   alloc((size_t)N_NODES * 4);
    int*    rp1  = (int*)   alloc((size_t)(N_NODES + 1) * 4);
    int*    rp2  = (int*)   alloc((size_t)(N_NODES + 1) * 4);
    int*    cur1 = (int*)   alloc((size_t)N_NODES * 4);
    int*    cur2 = (int*)   alloc((size_t)N_NODES * 4);
    int*    pre1 = (int*)   alloc((size_t)N_NODES * 4);
    int*    pre2 = (int*)   alloc((size_t)N_NODES * 4);
    int*    bs1  = (int*)   alloc(256 * 4);
    int*    bs2  = (int*)   alloc(256 * 4);
    int2*   adjw1= (int2*)  alloc((size_t)E1 * 8);
    int2*   adjw2= (int2*)  alloc((size_t)E2 * 8);
    ushort* Wt1  = (ushort*)alloc(512 * 512 * 2);
    ushort* Wt2  = (ushort*)alloc(256 * 512 * 2);
    ushort* Wt3  = (ushort*)alloc(512 * 256 * 2);
    ushort* Wt4  = (ushort*)alloc(256 * 512 * 2);

    const dim3 blk(256);
    const dim3 gblk(512);
    const int MT = MP / 128;                 // 391 row tiles
    const int GB = (N_NODES + 7) / 8;        // gather blocks (4 waves x 2 nodes)
    const int NB = (N_NODES + 255) / 256;    // 196 scan blocks

    // ---- CSR build for both edge sets ----
    hipMemsetAsync(deg1, 0, (size_t)N_NODES * 4, stream);
    hipMemsetAsync(deg2, 0, (size_t)N_NODES * 4, stream);
    deg_int_kernel<<<(E1 + 255) / 256, blk, 0, stream>>>(dst1, deg1, E1);
    deg_int_kernel<<<(E2 + 255) / 256, blk, 0, stream>>>(dst2, deg2, E2);
    inv_from_deg<<<(N_NODES + 255) / 256, blk, 0, stream>>>(deg1, inv1, N_NODES);
    inv_from_deg<<<(N_NODES + 255) / 256, blk, 0, stream>>>(deg2, inv2, N_NODES);
    scan1_kernel<<<NB, blk, 0, stream>>>(deg1, pre1, bs1, N_NODES);
    scan1_kernel<<<NB, blk, 0, stream>>>(deg2, pre2, bs2, N_NODES);
    scan2_kernel<<<1, blk, 0, stream>>>(bs1, NB, rp1 + N_NODES);
    scan2_kernel<<<1, blk, 0, stream>>>(bs2, NB, rp2 + N_NODES);
    scan3_kernel<<<NB, blk, 0, stream>>>(pre1, bs1, rp1, cur1, N_NODES);
    scan3_kernel<<<NB, blk, 0, stream>>>(pre2, bs2, rp2, cur2, N_NODES);
    fill_adj_kernel<<<(E1 + 255) / 256, blk, 0, stream>>>(src1, dst1, inv1, cur1, adjw1, E1);
    fill_adj_kernel<<<(E2 + 255) / 256, blk, 0, stream>>>(src2, dst2, inv2, cur2, adjw2, E2);

    // ---- weight prep + x -> bf16 ----
    transpose_kernel<<<(512 * 512 + 255) / 256, blk, 0, stream>>>(W1, Wt1, 512, 512);
    transpose_kernel<<<(512 * 256 + 255) / 256, blk, 0, stream>>>(W2, Wt2, 512, 256);
    transpose_kernel<<<(256 * 512 + 255) / 256, blk, 0, stream>>>(W3, Wt3, 256, 512);
    transpose_kernel<<<(512 * 256 + 255) / 256, blk, 0, stream>>>(W4, Wt4, 512, 256);
    f2b_kernel<<<(N_NODES * 512 + 255) / 256, blk, 0, stream>>>(x, Xb, N_NODES * 512);

    // ---- encoder 1, layer 1: h1 = x@W1 -> R0 ; a1 = relu(P1(h1)+b1) -> R1 (bf16, 2 col-blocks) ----
    gemm_kernel<<<dim3(4, MT), gblk, 0, stream>>>(Xb, Wt1, R0, nullptr, N_NODES, 512, 512, 0);
    gather_kernel<true, true, false, true><<<dim3(GB, 2), blk, 0, stream>>>(
        rp1, adjw1, R0, 512, inv1, b1, nullptr, R1, 512);

    // ---- encoder 1, layer 2: h2 = a1@W2 -> R0(256) ; z = relu(P1(h2)+b2) -> z f32 + zb -> R1 ----
    gemm_kernel<<<dim3(2, MT), gblk, 0, stream>>>(R1, Wt2, R0, nullptr, N_NODES, 512, 256, 0);
    gather_kernel<true, true, true, true><<<dim3(GB, 1), blk, 0, stream>>>(
        rp1, adjw1, R0, 256, inv1, b2, z, R1, 256);

    // ---- encoder 2, layer 1 (propagate-first): pz = P2(zb) -> R0(256) ; a3 = relu(pz@W3+b3) -> R1 ----
    gather_kernel<false, false, false, true><<<dim3(GB, 1), blk, 0, stream>>>(
        rp2, adjw2, R1, 256, inv2, nullptr, nullptr, R0, 256);
    gemm_kernel<<<dim3(4, MT), gblk, 0, stream>>>(R0, Wt3, R1, b3, N_NODES, 256, 512, 1);

    // ---- encoder 2, layer 2: h4 = a3@W4 -> R0(256) ; z_g = relu(P2(h4)+b4) -> z_g f32 ----
    gemm_kernel<<<dim3(2, MT), gblk, 0, stream>>>(R1, Wt4, R0, nullptr, N_NODES, 512, 256, 0);
    gather_kernel<true, true, true, false><<<dim3(GB, 1), blk, 0, stream>>>(
        rp2, adjw2, R0, 256, inv2, b4, z_g, nullptr, 256);
}

// Round 10
// 471.003 us; speedup vs baseline: 1.0684x; 1.0684x over previous
//
#include <hip/hip_runtime.h>

#define N_NODES 50000
#define MP 50048            // row-tile padding (128-multiple) for GEMM grids

typedef short short8 __attribute__((ext_vector_type(8)));
typedef float floatx4 __attribute__((ext_vector_type(4)));
typedef ushort u16x4 __attribute__((ext_vector_type(4)));
typedef ushort u16x8 __attribute__((ext_vector_type(8)));
typedef float f32x4 __attribute__((ext_vector_type(4)));

__device__ __forceinline__ float bf2f(ushort u) {
    union { unsigned int i; float f; } x; x.i = ((unsigned int)u) << 16; return x.f;
}
__device__ __forceinline__ ushort f2bf(float f) {
    union { float f; unsigned int i; } x; x.f = f;
    unsigned int r = x.i + 0x7FFFu + ((x.i >> 16) & 1u);
    return (ushort)(r >> 16);
}

// ---------- CSR build ----------
__global__ __launch_bounds__(256) void deg_int_kernel(const int* __restrict__ dst,
                                                      int* __restrict__ deg, int E) {
    int i = blockIdx.x * 256 + threadIdx.x;
    if (i < E) atomicAdd(&deg[dst[i]], 1);
}
__global__ __launch_bounds__(256) void inv_from_deg(const int* __restrict__ deg,
                                                    float* __restrict__ inv, int n) {
    int i = blockIdx.x * 256 + threadIdx.x;
    if (i < n) inv[i] = rsqrtf((float)deg[i] + 1.0f);
}

// ---- hierarchical exclusive scan (n <= 256*256) ----
__global__ __launch_bounds__(256) void scan1_kernel(const int* __restrict__ deg,
                                                    int* __restrict__ pre,
                                                    int* __restrict__ bsum, int n) {
    __shared__ int tmp[256];
    const int t = threadIdx.x;
    const int i = blockIdx.x * 256 + t;
    const int v = (i < n) ? deg[i] : 0;
    tmp[t] = v;
    __syncthreads();
#pragma unroll
    for (int d = 1; d < 256; d <<= 1) {
        int u = (t >= d) ? tmp[t - d] : 0;
        __syncthreads();
        tmp[t] += u;
        __syncthreads();
    }
    if (i < n) pre[i] = tmp[t] - v;           // exclusive within block
    if (t == 255) bsum[blockIdx.x] = tmp[255];
}
__global__ __launch_bounds__(256) void scan2_kernel(int* __restrict__ bsum, int nb,
                                                    int* __restrict__ row_ptr_n) {
    __shared__ int tmp[256];
    const int t = threadIdx.x;
    const int v = (t < nb) ? bsum[t] : 0;
    tmp[t] = v;
    __syncthreads();
#pragma unroll
    for (int d = 1; d < 256; d <<= 1) {
        int u = (t >= d) ? tmp[t - d] : 0;
        __syncthreads();
        tmp[t] += u;
        __syncthreads();
    }
    if (t < nb) bsum[t] = tmp[t] - v;         // exclusive block offsets
    if (t == 255) *row_ptr_n = tmp[255];      // grand total
}
__global__ __launch_bounds__(256) void scan3_kernel(const int* __restrict__ pre,
                                                    const int* __restrict__ bsum,
                                                    int* __restrict__ row_ptr,
                                                    int* __restrict__ cursor, int n) {
    const int i = blockIdx.x * 256 + threadIdx.x;
    if (i < n) {
        int v = pre[i] + bsum[blockIdx.x];
        row_ptr[i] = v;
        cursor[i] = v;
    }
}
// fill interleaved adjacency: adjw[pos] = (src, bits(invs[src]))
__global__ __launch_bounds__(256) void fill_adj_kernel(const int* __restrict__ src,
                                                       const int* __restrict__ dst,
                                                       const float* __restrict__ invs,
                                                       int* __restrict__ cursor,
                                                       int2* __restrict__ adjw, int E) {
    int i = blockIdx.x * 256 + threadIdx.x;
    if (i < E) {
        int s = src[i];
        int pos = atomicAdd(&cursor[dst[i]], 1);
        adjw[pos] = make_int2(s, __float_as_int(invs[s]));
    }
}

// ---------- weight prep ----------
__global__ __launch_bounds__(256) void transpose_kernel(const float* __restrict__ W,
                                                        ushort* __restrict__ Wt, int K, int N) {
    int idx = blockIdx.x * 256 + threadIdx.x;
    if (idx < K * N) {
        int k = idx / N, n = idx % N;
        Wt[n * K + k] = f2bf(W[idx]);
    }
}

// ---------- bf16 MFMA GEMM:  C[M,N] = A[M,K] @ Bt[N,K]^T ----------
// 128x128 tile, 8 waves (512 thr), wave = 64x32 quadrant -> 32 AGPR acc.
__global__ __launch_bounds__(512, 4) void gemm_kernel(
    const ushort* __restrict__ A, const ushort* __restrict__ Bt,
    ushort* __restrict__ C, const float* __restrict__ bias,
    int M, int K, int N, int do_relu)
{
    __shared__ __align__(16) ushort Alds[128 * 32];
    __shared__ __align__(16) ushort Blds[128 * 32];
    const int t = threadIdx.x;
    const int w = t >> 6, l = t & 63;
    const int m0 = blockIdx.y * 128;
    const int n0 = blockIdx.x * 128;
    const int wr = (w >> 2) * 64, wc = (w & 3) * 32;
    const int lhi = l >> 4, llo = l & 15;

    floatx4 acc[4][2] = {};

    const int srow = w * 16 + (l >> 2);      // 0..127
    const int scol = (l & 3) * 8;            // ushort offset within row
    int gr = m0 + srow; gr = gr < M ? gr : M - 1;
    const ushort* gA = A + (size_t)gr * K + scol;
    const ushort* gB = Bt + (size_t)(n0 + srow) * K + scol;
    ushort* lA = Alds + srow * 32 + scol;
    ushort* lB = Blds + srow * 32 + scol;

    const int nkt = K >> 5;
    for (int kt = 0; kt < nkt; ++kt) {
        const int k0 = kt << 5;
        __builtin_amdgcn_global_load_lds(
            (const __attribute__((address_space(1))) void*)(gA + k0),
            (__attribute__((address_space(3))) void*)lA, 16, 0, 0);
        __builtin_amdgcn_global_load_lds(
            (const __attribute__((address_space(1))) void*)(gB + k0),
            (__attribute__((address_space(3))) void*)lB, 16, 0, 0);
        __syncthreads();
        short8 av[4], bv[2];
#pragma unroll
        for (int m = 0; m < 4; ++m)
            av[m] = *reinterpret_cast<const short8*>(&Alds[(wr + m * 16 + llo) * 32 + lhi * 8]);
#pragma unroll
        for (int n = 0; n < 2; ++n)
            bv[n] = *reinterpret_cast<const short8*>(&Blds[(wc + n * 16 + llo) * 32 + lhi * 8]);
#pragma unroll
        for (int m = 0; m < 4; ++m)
#pragma unroll
            for (int n = 0; n < 2; ++n)
                acc[m][n] = __builtin_amdgcn_mfma_f32_16x16x32_bf16(av[m], bv[n], acc[m][n], 0, 0, 0);
        __syncthreads();
    }

    const int lr = lhi * 4;
#pragma unroll
    for (int m = 0; m < 4; ++m) {
#pragma unroll
        for (int n = 0; n < 2; ++n) {
            int gcol = n0 + wc + n * 16 + llo;
            float badd = bias ? bias[gcol] : 0.0f;
#pragma unroll
            for (int j = 0; j < 4; ++j) {
                int grow = m0 + wr + m * 16 + lr + j;
                if (grow < M) {
                    float v = acc[m][n][j] + badd;
                    if (do_relu) v = fmaxf(v, 0.0f);
                    C[(size_t)grow * N + gcol] = f2bf(v);
                }
            }
        }
    }
}

// ---------- f32-A variant (GEMM1): A is f32, converted to bf16 during staging ----------
__global__ __launch_bounds__(512, 4) void gemm_f32a_kernel(
    const float* __restrict__ A, const ushort* __restrict__ Bt,
    ushort* __restrict__ C, int M, int K, int N)
{
    __shared__ __align__(16) ushort Alds[128 * 32];
    __shared__ __align__(16) ushort Blds[128 * 32];
    const int t = threadIdx.x;
    const int w = t >> 6, l = t & 63;
    const int m0 = blockIdx.y * 128;
    const int n0 = blockIdx.x * 128;
    const int wr = (w >> 2) * 64, wc = (w & 3) * 32;
    const int lhi = l >> 4, llo = l & 15;

    floatx4 acc[4][2] = {};

    const int srow = w * 16 + (l >> 2);
    const int scol = (l & 3) * 8;
    int gr = m0 + srow; gr = gr < M ? gr : M - 1;
    const float*  gA = A + (size_t)gr * K + scol;
    const ushort* gB = Bt + (size_t)(n0 + srow) * K + scol;
    ushort* lA = Alds + srow * 32 + scol;
    ushort* lB = Blds + srow * 32 + scol;

    const int nkt = K >> 5;
    for (int kt = 0; kt < nkt; ++kt) {
        const int k0 = kt << 5;
        __builtin_amdgcn_global_load_lds(
            (const __attribute__((address_space(1))) void*)(gB + k0),
            (__attribute__((address_space(3))) void*)lB, 16, 0, 0);
        // A: f32 register staging + convert
        const f32x4 alo = *reinterpret_cast<const f32x4*>(gA + k0);
        const f32x4 ahi = *reinterpret_cast<const f32x4*>(gA + k0 + 4);
        u16x8 ab;
#pragma unroll
        for (int k = 0; k < 4; ++k) { ab[k] = f2bf(alo[k]); ab[k + 4] = f2bf(ahi[k]); }
        *reinterpret_cast<u16x8*>(lA) = ab;
        __syncthreads();
        short8 av[4], bv[2];
#pragma unroll
        for (int m = 0; m < 4; ++m)
            av[m] = *reinterpret_cast<const short8*>(&Alds[(wr + m * 16 + llo) * 32 + lhi * 8]);
#pragma unroll
        for (int n = 0; n < 2; ++n)
            bv[n] = *reinterpret_cast<const short8*>(&Blds[(wc + n * 16 + llo) * 32 + lhi * 8]);
#pragma unroll
        for (int m = 0; m < 4; ++m)
#pragma unroll
            for (int n = 0; n < 2; ++n)
                acc[m][n] = __builtin_amdgcn_mfma_f32_16x16x32_bf16(av[m], bv[n], acc[m][n], 0, 0, 0);
        __syncthreads();
    }

    const int lr = lhi * 4;
#pragma unroll
    for (int m = 0; m < 4; ++m) {
#pragma unroll
        for (int n = 0; n < 2; ++n) {
            int gcol = n0 + wc + n * 16 + llo;
#pragma unroll
            for (int j = 0; j < 4; ++j) {
                int grow = m0 + wr + m * 16 + lr + j;
                if (grow < M)
                    C[(size_t)grow * N + gcol] = f2bf(acc[m][n][j]);
            }
        }
    }
}

// ---------- 512-wide CSR gather (layer 1): one node/wave, lane owns 8 of 512 ch ----------
// out = relu( sum_e h[adj]*w*invd + h[node]*invd^2 + bias )  -> bf16
__global__ __launch_bounds__(256) void gather512_kernel(
    const int* __restrict__ row_ptr, const int2* __restrict__ adjw,
    const ushort* __restrict__ h, const float* __restrict__ invs,
    const float* __restrict__ bias, ushort* __restrict__ outB)
{
    const int wv = threadIdx.x >> 6, l = threadIdx.x & 63;
    const int node = blockIdx.x * 4 + wv;
    if (node >= N_NODES) return;
    const int c0 = l * 8;
    const int beg = row_ptr[node], end = row_ptr[node + 1];
    const float invd = invs[node];

    float a0[8] = {}, a1[8] = {}, a2[8] = {}, a3[8] = {};
    int e = beg;
    for (; e + 4 <= end; e += 4) {
        const int2 w0 = adjw[e], w1 = adjw[e+1], w2 = adjw[e+2], w3 = adjw[e+3];
        const float f0 = __int_as_float(w0.y) * invd, f1 = __int_as_float(w1.y) * invd;
        const float f2 = __int_as_float(w2.y) * invd, f3 = __int_as_float(w3.y) * invd;
        const u16x8 h0 = *reinterpret_cast<const u16x8*>(h + (unsigned)(w0.x * 512 + c0));
        const u16x8 h1 = *reinterpret_cast<const u16x8*>(h + (unsigned)(w1.x * 512 + c0));
        const u16x8 h2 = *reinterpret_cast<const u16x8*>(h + (unsigned)(w2.x * 512 + c0));
        const u16x8 h3 = *reinterpret_cast<const u16x8*>(h + (unsigned)(w3.x * 512 + c0));
#pragma unroll
        for (int k = 0; k < 8; ++k) {
            a0[k] += bf2f(h0[k]) * f0;
            a1[k] += bf2f(h1[k]) * f1;
            a2[k] += bf2f(h2[k]) * f2;
            a3[k] += bf2f(h3[k]) * f3;
        }
    }
    if (e + 2 <= end) {
        const int2 w0 = adjw[e], w1 = adjw[e+1];
        const float f0 = __int_as_float(w0.y) * invd, f1 = __int_as_float(w1.y) * invd;
        const u16x8 h0 = *reinterpret_cast<const u16x8*>(h + (unsigned)(w0.x * 512 + c0));
        const u16x8 h1 = *reinterpret_cast<const u16x8*>(h + (unsigned)(w1.x * 512 + c0));
#pragma unroll
        for (int k = 0; k < 8; ++k) {
            a0[k] += bf2f(h0[k]) * f0;
            a1[k] += bf2f(h1[k]) * f1;
        }
        e += 2;
    }
    if (e < end) {
        const int2 w0 = adjw[e];
        const float f0 = __int_as_float(w0.y) * invd;
        const u16x8 h0 = *reinterpret_cast<const u16x8*>(h + (unsigned)(w0.x * 512 + c0));
#pragma unroll
        for (int k = 0; k < 8; ++k) a0[k] += bf2f(h0[k]) * f0;
    }
    {
        const float ws = invd * invd;
        const u16x8 hs = *reinterpret_cast<const u16x8*>(h + (unsigned)(node * 512 + c0));
#pragma unroll
        for (int k = 0; k < 8; ++k)
            a0[k] = (a0[k] + a1[k]) + (a2[k] + a3[k]) + bf2f(hs[k]) * ws;
    }
    u16x8 o;
#pragma unroll
    for (int k = 0; k < 8; ++k)
        o[k] = f2bf(fmaxf(a0[k] + bias[c0 + k], 0.0f));
    *reinterpret_cast<u16x8*>(outB + (size_t)node * 512 + c0) = o;
}

// ---------- 256-wide CSR gather + fused epilogue (r8 structure, int2 adjw) ----------
template<bool RELU, bool BIAS, bool WF, bool WB>
__global__ __launch_bounds__(256) void gather_kernel(
    const int* __restrict__ row_ptr, const int2* __restrict__ adjw,
    const ushort* __restrict__ h, int ldh,
    const float* __restrict__ invs, const float* __restrict__ bias,
    float* __restrict__ outF, ushort* __restrict__ outB, int ldo)
{
    const int wv = threadIdx.x >> 6, l = threadIdx.x & 63;
    const int node = blockIdx.x * 4 + wv;
    if (node >= N_NODES) return;
    const int c0 = l * 4;
    const int beg = row_ptr[node], end = row_ptr[node + 1];
    const float invd = invs[node];

    float a0[4] = {}, a1[4] = {}, a2[4] = {}, a3[4] = {};
    int e = beg;
    for (; e + 4 <= end; e += 4) {
        const int2 w0 = adjw[e], w1 = adjw[e+1], w2 = adjw[e+2], w3 = adjw[e+3];
        const float f0 = __int_as_float(w0.y) * invd, f1 = __int_as_float(w1.y) * invd;
        const float f2 = __int_as_float(w2.y) * invd, f3 = __int_as_float(w3.y) * invd;
        const u16x4 h0 = *reinterpret_cast<const u16x4*>(h + (unsigned)(w0.x * ldh + c0));
        const u16x4 h1 = *reinterpret_cast<const u16x4*>(h + (unsigned)(w1.x * ldh + c0));
        const u16x4 h2 = *reinterpret_cast<const u16x4*>(h + (unsigned)(w2.x * ldh + c0));
        const u16x4 h3 = *reinterpret_cast<const u16x4*>(h + (unsigned)(w3.x * ldh + c0));
#pragma unroll
        for (int k = 0; k < 4; ++k) {
            a0[k] += bf2f(h0[k]) * f0;
            a1[k] += bf2f(h1[k]) * f1;
            a2[k] += bf2f(h2[k]) * f2;
            a3[k] += bf2f(h3[k]) * f3;
        }
    }
    if (e + 2 <= end) {
        const int2 w0 = adjw[e], w1 = adjw[e+1];
        const float f0 = __int_as_float(w0.y) * invd, f1 = __int_as_float(w1.y) * invd;
        const u16x4 h0 = *reinterpret_cast<const u16x4*>(h + (unsigned)(w0.x * ldh + c0));
        const u16x4 h1 = *reinterpret_cast<const u16x4*>(h + (unsigned)(w1.x * ldh + c0));
#pragma unroll
        for (int k = 0; k < 4; ++k) {
            a0[k] += bf2f(h0[k]) * f0;
            a1[k] += bf2f(h1[k]) * f1;
        }
        e += 2;
    }
    if (e < end) {
        const int2 w0 = adjw[e];
        const float f0 = __int_as_float(w0.y) * invd;
        const u16x4 h0 = *reinterpret_cast<const u16x4*>(h + (unsigned)(w0.x * ldh + c0));
#pragma unroll
        for (int k = 0; k < 4; ++k) a0[k] += bf2f(h0[k]) * f0;
    }
    {
        const float ws = invd * invd;
        const u16x4 hs = *reinterpret_cast<const u16x4*>(h + (unsigned)(node * ldh + c0));
#pragma unroll
        for (int k = 0; k < 4; ++k)
            a0[k] = (a0[k] + a1[k]) + (a2[k] + a3[k]) + bf2f(hs[k]) * ws;
    }
#pragma unroll
    for (int k = 0; k < 4; ++k) {
        float v = a0[k];
        if (BIAS) v += bias[c0 + k];
        if (RELU) v = fmaxf(v, 0.0f);
        a0[k] = v;
    }
    if (WF)
        *reinterpret_cast<f32x4*>(outF + (size_t)node * ldo + c0) = *reinterpret_cast<f32x4*>(a0);
    if (WB) {
        u16x4 o;
#pragma unroll
        for (int k = 0; k < 4; ++k) o[k] = f2bf(a0[k]);
        *reinterpret_cast<u16x4*>(outB + (size_t)node * ldo + c0) = o;
    }
}

extern "C" void kernel_launch(void* const* d_in, const int* in_sizes, int n_in,
                              void* d_out, int out_size, void* d_ws, size_t ws_size,
                              hipStream_t stream)
{
    const float* x  = (const float*)d_in[0];
    const int* ei1  = (const int*)d_in[1];
    const int* ei2  = (const int*)d_in[2];
    const float* W1 = (const float*)d_in[3];
    const float* b1 = (const float*)d_in[4];
    const float* W2 = (const float*)d_in[5];
    const float* b2 = (const float*)d_in[6];
    const float* W3 = (const float*)d_in[7];
    const float* b3 = (const float*)d_in[8];
    const float* W4 = (const float*)d_in[9];
    const float* b4 = (const float*)d_in[10];
    float* z   = (float*)d_out;                        // [50000,256] f32
    float* z_g = z + (size_t)N_NODES * 256;            // [50000,256] f32

    const int E1 = in_sizes[1] / 2, E2 = in_sizes[2] / 2;
    const int* src1 = ei1;  const int* dst1 = ei1 + E1;
    const int* src2 = ei2;  const int* dst2 = ei2 + E2;

    // ---- alias on d_out: R1 = z_g half, used as bf16 ping buffer until final gather ----
    ushort* R1 = (ushort*)z_g;

    // ---- workspace (~62 MB) ----
    char* ws = (char*)d_ws;
    size_t off = 0;
    auto alloc = [&](size_t bytes) { void* p = ws + off; off += (bytes + 255) & ~(size_t)255; return p; };
    ushort* R0   = (ushort*)alloc((size_t)N_NODES * 512 * 2);
    float*  inv1 = (float*) alloc((size_t)N_NODES * 4);
    float*  inv2 = (float*) alloc((size_t)N_NODES * 4);
    int*    deg1 = (int*)   alloc((size_t)N_NODES * 4);
    int*    deg2 = (int*)   alloc((size_t)N_NODES * 4);
    int*    rp1  = (int*)   alloc((size_t)(N_NODES + 1) * 4);
    int*    rp2  = (int*)   alloc((size_t)(N_NODES + 1) * 4);
    int*    cur1 = (int*)   alloc((size_t)N_NODES * 4);
    int*    cur2 = (int*)   alloc((size_t)N_NODES * 4);
    int*    pre1 = (int*)   alloc((size_t)N_NODES * 4);
    int*    pre2 = (int*)   alloc((size_t)N_NODES * 4);
    int*    bs1  = (int*)   alloc(256 * 4);
    int*    bs2  = (int*)   alloc(256 * 4);
    int2*   adjw1= (int2*)  alloc((size_t)E1 * 8);
    int2*   adjw2= (int2*)  alloc((size_t)E2 * 8);
    ushort* Wt1  = (ushort*)alloc(512 * 512 * 2);
    ushort* Wt2  = (ushort*)alloc(256 * 512 * 2);
    ushort* Wt3  = (ushort*)alloc(512 * 256 * 2);
    ushort* Wt4  = (ushort*)alloc(256 * 512 * 2);

    const dim3 blk(256);
    const dim3 gblk(512);
    const int MT = MP / 128;                 // 391 row tiles
    const int GB = (N_NODES + 3) / 4;        // gather blocks (4 waves, 1 node/wave)
    const int NB = (N_NODES + 255) / 256;    // 196 scan blocks

    // ---- CSR build for both edge sets ----
    hipMemsetAsync(deg1, 0, (size_t)N_NODES * 4, stream);
    hipMemsetAsync(deg2, 0, (size_t)N_NODES * 4, stream);
    deg_int_kernel<<<(E1 + 255) / 256, blk, 0, stream>>>(dst1, deg1, E1);
    deg_int_kernel<<<(E2 + 255) / 256, blk, 0, stream>>>(dst2, deg2, E2);
    inv_from_deg<<<(N_NODES + 255) / 256, blk, 0, stream>>>(deg1, inv1, N_NODES);
    inv_from_deg<<<(N_NODES + 255) / 256, blk, 0, stream>>>(deg2, inv2, N_NODES);
    scan1_kernel<<<NB, blk, 0, stream>>>(deg1, pre1, bs1, N_NODES);
    scan1_kernel<<<NB, blk, 0, stream>>>(deg2, pre2, bs2, N_NODES);
    scan2_kernel<<<1, blk, 0, stream>>>(bs1, NB, rp1 + N_NODES);
    scan2_kernel<<<1, blk, 0, stream>>>(bs2, NB, rp2 + N_NODES);
    scan3_kernel<<<NB, blk, 0, stream>>>(pre1, bs1, rp1, cur1, N_NODES);
    scan3_kernel<<<NB, blk, 0, stream>>>(pre2, bs2, rp2, cur2, N_NODES);
    fill_adj_kernel<<<(E1 + 255) / 256, blk, 0, stream>>>(src1, dst1, inv1, cur1, adjw1, E1);
    fill_adj_kernel<<<(E2 + 255) / 256, blk, 0, stream>>>(src2, dst2, inv2, cur2, adjw2, E2);

    // ---- weight prep ----
    transpose_kernel<<<(512 * 512 + 255) / 256, blk, 0, stream>>>(W1, Wt1, 512, 512);
    transpose_kernel<<<(512 * 256 + 255) / 256, blk, 0, stream>>>(W2, Wt2, 512, 256);
    transpose_kernel<<<(256 * 512 + 255) / 256, blk, 0, stream>>>(W3, Wt3, 256, 512);
    transpose_kernel<<<(512 * 256 + 255) / 256, blk, 0, stream>>>(W4, Wt4, 512, 256);

    // ---- encoder 1, layer 1: h1 = x@W1 -> R0 (f32-A GEMM) ; a1 = relu(P1(h1)+b1) -> R1 ----
    gemm_f32a_kernel<<<dim3(4, MT), gblk, 0, stream>>>(x, Wt1, R0, N_NODES, 512, 512);
    gather512_kernel<<<GB, blk, 0, stream>>>(rp1, adjw1, R0, inv1, b1, R1);

    // ---- encoder 1, layer 2: h2 = a1@W2 -> R0(256) ; z = relu(P1(h2)+b2) -> z f32 + zb -> R1 ----
    gemm_kernel<<<dim3(2, MT), gblk, 0, stream>>>(R1, Wt2, R0, nullptr, N_NODES, 512, 256, 0);
    gather_kernel<true, true, true, true><<<GB, blk, 0, stream>>>(
        rp1, adjw1, R0, 256, inv1, b2, z, R1, 256);

    // ---- encoder 2, layer 1 (propagate-first): pz = P2(zb) -> R0(256) ; a3 = relu(pz@W3+b3) -> R1 ----
    gather_kernel<false, false, false, true><<<GB, blk, 0, stream>>>(
        rp2, adjw2, R1, 256, inv2, nullptr, nullptr, R0, 256);
    gemm_kernel<<<dim3(4, MT), gblk, 0, stream>>>(R0, Wt3, R1, b3, N_NODES, 256, 512, 1);

    // ---- encoder 2, layer 2: h4 = a3@W4 -> R0(256) ; z_g = relu(P2(h4)+b4) -> z_g f32 ----
    gemm_kernel<<<dim3(2, MT), gblk, 0, stream>>>(R1, Wt4, R0, nullptr, N_NODES, 512, 256, 0);
    gather_kernel<true, true, true, false><<<GB, blk, 0, stream>>>(
        rp2, adjw2, R0, 256, inv2, b4, z_g, nullptr, 256);
}

// Round 11
// 463.167 us; speedup vs baseline: 1.0864x; 1.0169x over previous
//
#include <hip/hip_runtime.h>

#define N_NODES 50000
#define MP 50048            // row-tile padding (128-multiple) for GEMM grids

typedef short short8 __attribute__((ext_vector_type(8)));
typedef float floatx4 __attribute__((ext_vector_type(4)));
typedef ushort u16x4 __attribute__((ext_vector_type(4)));
typedef ushort u16x8 __attribute__((ext_vector_type(8)));
typedef float f32x4 __attribute__((ext_vector_type(4)));

__device__ __forceinline__ float bf2f(ushort u) {
    union { unsigned int i; float f; } x; x.i = ((unsigned int)u) << 16; return x.f;
}
__device__ __forceinline__ ushort f2bf(float f) {
    union { float f; unsigned int i; } x; x.f = f;
    unsigned int r = x.i + 0x7FFFu + ((x.i >> 16) & 1u);
    return (ushort)(r >> 16);
}

// ---------- combined CSR build (both edge sets in one launch) ----------
__global__ __launch_bounds__(256) void deg_both_kernel(const int* __restrict__ dst1, int E1,
                                                       const int* __restrict__ dst2, int E2,
                                                       int* __restrict__ deg /* [2*N] */) {
    int i = blockIdx.x * 256 + threadIdx.x;
    if (i < E1) atomicAdd(&deg[dst1[i]], 1);
    else if (i - E1 < E2) atomicAdd(&deg[N_NODES + dst2[i - E1]], 1);
}
__global__ __launch_bounds__(256) void inv_both_kernel(const int* __restrict__ deg,
                                                       float* __restrict__ inv /* [2*N] */) {
    int i = blockIdx.x * 256 + threadIdx.x;
    if (i < 2 * N_NODES) inv[i] = rsqrtf((float)deg[i] + 1.0f);
}
// stage 1: per-block local exclusive scan; grid.y selects edge set
__global__ __launch_bounds__(256) void scan1_kernel(const int* __restrict__ deg,
                                                    int* __restrict__ pre,
                                                    int* __restrict__ bsum, int n) {
    __shared__ int tmp[256];
    const int set = blockIdx.y;
    deg += set * n; pre += set * n; bsum += set * 256;
    const int t = threadIdx.x;
    const int i = blockIdx.x * 256 + t;
    const int v = (i < n) ? deg[i] : 0;
    tmp[t] = v;
    __syncthreads();
#pragma unroll
    for (int d = 1; d < 256; d <<= 1) {
        int u = (t >= d) ? tmp[t - d] : 0;
        __syncthreads();
        tmp[t] += u;
        __syncthreads();
    }
    if (i < n) pre[i] = tmp[t] - v;
    if (t == 255) bsum[blockIdx.x] = tmp[255];
}
// stage 2: blockIdx.x selects edge set
__global__ __launch_bounds__(256) void scan2_kernel(int* __restrict__ bsum, int nb) {
    __shared__ int tmp[256];
    bsum += blockIdx.x * 256;
    const int t = threadIdx.x;
    const int v = (t < nb) ? bsum[t] : 0;
    tmp[t] = v;
    __syncthreads();
#pragma unroll
    for (int d = 1; d < 256; d <<= 1) {
        int u = (t >= d) ? tmp[t - d] : 0;
        __syncthreads();
        tmp[t] += u;
        __syncthreads();
    }
    if (t < nb) bsum[t] = tmp[t] - v;
}
// stage 3: add block offset -> row_ptr + cursor; grid.y selects edge set
__global__ __launch_bounds__(256) void scan3_kernel(const int* __restrict__ pre,
                                                    const int* __restrict__ bsum,
                                                    int* __restrict__ rp1, int* __restrict__ cur1,
                                                    int* __restrict__ rp2, int* __restrict__ cur2,
                                                    int n) {
    const int set = blockIdx.y;
    int* rp  = set ? rp2 : rp1;
    int* cur = set ? cur2 : cur1;
    const int i = blockIdx.x * 256 + threadIdx.x;
    if (i < n) {
        int v = pre[set * n + i] + bsum[set * 256 + blockIdx.x];
        rp[i] = v;
        cur[i] = v;
    }
}
// fill both adjacency arrays: adjw[pos] = (src, bits(invs[src]))
__global__ __launch_bounds__(256) void fill_both_kernel(
    const int* __restrict__ src1, const int* __restrict__ dst1, int E1,
    const int* __restrict__ src2, const int* __restrict__ dst2, int E2,
    const float* __restrict__ inv /* [2*N] */,
    int* __restrict__ cur1, int* __restrict__ cur2,
    int2* __restrict__ adjw1, int2* __restrict__ adjw2) {
    int i = blockIdx.x * 256 + threadIdx.x;
    if (i < E1) {
        int s = src1[i];
        int pos = atomicAdd(&cur1[dst1[i]], 1);
        adjw1[pos] = make_int2(s, __float_as_int(inv[s]));
    } else if (i - E1 < E2) {
        int j = i - E1;
        int s = src2[j];
        int pos = atomicAdd(&cur2[dst2[j]], 1);
        adjw2[pos] = make_int2(s, __float_as_int(inv[N_NODES + s]));
    }
}

// ---------- combined weight transpose (all 4 weights, f32 -> bf16) ----------
__global__ __launch_bounds__(256) void transpose4_kernel(
    const float* __restrict__ W1, ushort* __restrict__ Wt1,
    const float* __restrict__ W2, ushort* __restrict__ Wt2,
    const float* __restrict__ W3, ushort* __restrict__ Wt3,
    const float* __restrict__ W4, ushort* __restrict__ Wt4) {
    int idx = blockIdx.x * 256 + threadIdx.x;
    const float* W; ushort* Wt; int K, N;
    if (idx < 262144)      { W = W1; Wt = Wt1; K = 512; N = 512; }
    else if (idx < 393216) { W = W2; Wt = Wt2; K = 512; N = 256; idx -= 262144; }
    else if (idx < 524288) { W = W3; Wt = Wt3; K = 256; N = 512; idx -= 393216; }
    else                   { W = W4; Wt = Wt4; K = 512; N = 256; idx -= 524288; }
    int k = idx / N, n = idx % N;
    Wt[n * K + k] = f2bf(W[idx]);
}

// ---------- f32 -> bf16, vectorized (4 elem/thread) ----------
__global__ __launch_bounds__(256) void f2b_kernel(const float* __restrict__ in,
                                                  ushort* __restrict__ out, int n4) {
    int i = blockIdx.x * 256 + threadIdx.x;
    if (i < n4) {
        const f32x4 v = *reinterpret_cast<const f32x4*>(in + i * 4);
        u16x4 o;
#pragma unroll
        for (int k = 0; k < 4; ++k) o[k] = f2bf(v[k]);
        *reinterpret_cast<u16x4*>(out + i * 4) = o;
    }
}

// ---------- bf16 MFMA GEMM:  C[M,N] = A[M,K] @ Bt[N,K]^T ----------
// 128x128 tile, 8 waves (512 thr), wave = 64x32 quadrant -> 32 AGPR acc.
__global__ __launch_bounds__(512, 4) void gemm_kernel(
    const ushort* __restrict__ A, const ushort* __restrict__ Bt,
    ushort* __restrict__ C, const float* __restrict__ bias,
    int M, int K, int N, int do_relu)
{
    __shared__ __align__(16) ushort Alds[128 * 32];
    __shared__ __align__(16) ushort Blds[128 * 32];
    const int t = threadIdx.x;
    const int w = t >> 6, l = t & 63;
    const int m0 = blockIdx.y * 128;
    const int n0 = blockIdx.x * 128;
    const int wr = (w >> 2) * 64, wc = (w & 3) * 32;
    const int lhi = l >> 4, llo = l & 15;

    floatx4 acc[4][2] = {};

    const int srow = w * 16 + (l >> 2);      // 0..127
    const int scol = (l & 3) * 8;            // ushort offset within row
    int gr = m0 + srow; gr = gr < M ? gr : M - 1;
    const ushort* gA = A + (size_t)gr * K + scol;
    const ushort* gB = Bt + (size_t)(n0 + srow) * K + scol;
    ushort* lA = Alds + srow * 32 + scol;
    ushort* lB = Blds + srow * 32 + scol;

    const int nkt = K >> 5;
    for (int kt = 0; kt < nkt; ++kt) {
        const int k0 = kt << 5;
        __builtin_amdgcn_global_load_lds(
            (const __attribute__((address_space(1))) void*)(gA + k0),
            (__attribute__((address_space(3))) void*)lA, 16, 0, 0);
        __builtin_amdgcn_global_load_lds(
            (const __attribute__((address_space(1))) void*)(gB + k0),
            (__attribute__((address_space(3))) void*)lB, 16, 0, 0);
        __syncthreads();
        short8 av[4], bv[2];
#pragma unroll
        for (int m = 0; m < 4; ++m)
            av[m] = *reinterpret_cast<const short8*>(&Alds[(wr + m * 16 + llo) * 32 + lhi * 8]);
#pragma unroll
        for (int n = 0; n < 2; ++n)
            bv[n] = *reinterpret_cast<const short8*>(&Blds[(wc + n * 16 + llo) * 32 + lhi * 8]);
#pragma unroll
        for (int m = 0; m < 4; ++m)
#pragma unroll
            for (int n = 0; n < 2; ++n)
                acc[m][n] = __builtin_amdgcn_mfma_f32_16x16x32_bf16(av[m], bv[n], acc[m][n], 0, 0, 0);
        __syncthreads();
    }

    const int lr = lhi * 4;
#pragma unroll
    for (int m = 0; m < 4; ++m) {
#pragma unroll
        for (int n = 0; n < 2; ++n) {
            int gcol = n0 + wc + n * 16 + llo;
            float badd = bias ? bias[gcol] : 0.0f;
#pragma unroll
            for (int j = 0; j < 4; ++j) {
                int grow = m0 + wr + m * 16 + lr + j;
                if (grow < M) {
                    float v = acc[m][n][j] + badd;
                    if (do_relu) v = fmaxf(v, 0.0f);
                    C[(size_t)grow * N + gcol] = f2bf(v);
                }
            }
        }
    }
}

// ---------- 512-wide CSR gather (layer 1): one node/wave, lane owns 8 of 512 ch ----------
__global__ __launch_bounds__(256) void gather512_kernel(
    const int* __restrict__ row_ptr, const int2* __restrict__ adjw,
    const ushort* __restrict__ h, const float* __restrict__ invs,
    const float* __restrict__ bias, ushort* __restrict__ outB)
{
    const int wv = threadIdx.x >> 6, l = threadIdx.x & 63;
    const int node = blockIdx.x * 4 + wv;
    if (node >= N_NODES) return;
    const int c0 = l * 8;
    const int beg = row_ptr[node], end = row_ptr[node + 1];
    const float invd = invs[node];

    float a0[8] = {}, a1[8] = {}, a2[8] = {}, a3[8] = {};
    int e = beg;
    for (; e + 4 <= end; e += 4) {
        const int2 w0 = adjw[e], w1 = adjw[e+1], w2 = adjw[e+2], w3 = adjw[e+3];
        const float f0 = __int_as_float(w0.y) * invd, f1 = __int_as_float(w1.y) * invd;
        const float f2 = __int_as_float(w2.y) * invd, f3 = __int_as_float(w3.y) * invd;
        const u16x8 h0 = *reinterpret_cast<const u16x8*>(h + (unsigned)(w0.x * 512 + c0));
        const u16x8 h1 = *reinterpret_cast<const u16x8*>(h + (unsigned)(w1.x * 512 + c0));
        const u16x8 h2 = *reinterpret_cast<const u16x8*>(h + (unsigned)(w2.x * 512 + c0));
        const u16x8 h3 = *reinterpret_cast<const u16x8*>(h + (unsigned)(w3.x * 512 + c0));
#pragma unroll
        for (int k = 0; k < 8; ++k) {
            a0[k] += bf2f(h0[k]) * f0;
            a1[k] += bf2f(h1[k]) * f1;
            a2[k] += bf2f(h2[k]) * f2;
            a3[k] += bf2f(h3[k]) * f3;
        }
    }
    if (e + 2 <= end) {
        const int2 w0 = adjw[e], w1 = adjw[e+1];
        const float f0 = __int_as_float(w0.y) * invd, f1 = __int_as_float(w1.y) * invd;
        const u16x8 h0 = *reinterpret_cast<const u16x8*>(h + (unsigned)(w0.x * 512 + c0));
        const u16x8 h1 = *reinterpret_cast<const u16x8*>(h + (unsigned)(w1.x * 512 + c0));
#pragma unroll
        for (int k = 0; k < 8; ++k) {
            a0[k] += bf2f(h0[k]) * f0;
            a1[k] += bf2f(h1[k]) * f1;
        }
        e += 2;
    }
    if (e < end) {
        const int2 w0 = adjw[e];
        const float f0 = __int_as_float(w0.y) * invd;
        const u16x8 h0 = *reinterpret_cast<const u16x8*>(h + (unsigned)(w0.x * 512 + c0));
#pragma unroll
        for (int k = 0; k < 8; ++k) a0[k] += bf2f(h0[k]) * f0;
    }
    {
        const float ws = invd * invd;
        const u16x8 hs = *reinterpret_cast<const u16x8*>(h + (unsigned)(node * 512 + c0));
#pragma unroll
        for (int k = 0; k < 8; ++k)
            a0[k] = (a0[k] + a1[k]) + (a2[k] + a3[k]) + bf2f(hs[k]) * ws;
    }
    u16x8 o;
#pragma unroll
    for (int k = 0; k < 8; ++k)
        o[k] = f2bf(fmaxf(a0[k] + bias[c0 + k], 0.0f));
    *reinterpret_cast<u16x8*>(outB + (size_t)node * 512 + c0) = o;
}

// ---------- 256-wide CSR gather + fused epilogue ----------
template<bool RELU, bool BIAS, bool WF, bool WB>
__global__ __launch_bounds__(256) void gather_kernel(
    const int* __restrict__ row_ptr, const int2* __restrict__ adjw,
    const ushort* __restrict__ h, int ldh,
    const float* __restrict__ invs, const float* __restrict__ bias,
    float* __restrict__ outF, ushort* __restrict__ outB, int ldo)
{
    const int wv = threadIdx.x >> 6, l = threadIdx.x & 63;
    const int node = blockIdx.x * 4 + wv;
    if (node >= N_NODES) return;
    const int c0 = l * 4;
    const int beg = row_ptr[node], end = row_ptr[node + 1];
    const float invd = invs[node];

    float a0[4] = {}, a1[4] = {}, a2[4] = {}, a3[4] = {};
    int e = beg;
    for (; e + 4 <= end; e += 4) {
        const int2 w0 = adjw[e], w1 = adjw[e+1], w2 = adjw[e+2], w3 = adjw[e+3];
        const float f0 = __int_as_float(w0.y) * invd, f1 = __int_as_float(w1.y) * invd;
        const float f2 = __int_as_float(w2.y) * invd, f3 = __int_as_float(w3.y) * invd;
        const u16x4 h0 = *reinterpret_cast<const u16x4*>(h + (unsigned)(w0.x * ldh + c0));
        const u16x4 h1 = *reinterpret_cast<const u16x4*>(h + (unsigned)(w1.x * ldh + c0));
        const u16x4 h2 = *reinterpret_cast<const u16x4*>(h + (unsigned)(w2.x * ldh + c0));
        const u16x4 h3 = *reinterpret_cast<const u16x4*>(h + (unsigned)(w3.x * ldh + c0));
#pragma unroll
        for (int k = 0; k < 4; ++k) {
            a0[k] += bf2f(h0[k]) * f0;
            a1[k] += bf2f(h1[k]) * f1;
            a2[k] += bf2f(h2[k]) * f2;
            a3[k] += bf2f(h3[k]) * f3;
        }
    }
    if (e + 2 <= end) {
        const int2 w0 = adjw[e], w1 = adjw[e+1];
        const float f0 = __int_as_float(w0.y) * invd, f1 = __int_as_float(w1.y) * invd;
        const u16x4 h0 = *reinterpret_cast<const u16x4*>(h + (unsigned)(w0.x * ldh + c0));
        const u16x4 h1 = *reinterpret_cast<const u16x4*>(h + (unsigned)(w1.x * ldh + c0));
#pragma unroll
        for (int k = 0; k < 4; ++k) {
            a0[k] += bf2f(h0[k]) * f0;
            a1[k] += bf2f(h1[k]) * f1;
        }
        e += 2;
    }
    if (e < end) {
        const int2 w0 = adjw[e];
        const float f0 = __int_as_float(w0.y) * invd;
        const u16x4 h0 = *reinterpret_cast<const u16x4*>(h + (unsigned)(w0.x * ldh + c0));
#pragma unroll
        for (int k = 0; k < 4; ++k) a0[k] += bf2f(h0[k]) * f0;
    }
    {
        const float ws = invd * invd;
        const u16x4 hs = *reinterpret_cast<const u16x4*>(h + (unsigned)(node * ldh + c0));
#pragma unroll
        for (int k = 0; k < 4; ++k)
            a0[k] = (a0[k] + a1[k]) + (a2[k] + a3[k]) + bf2f(hs[k]) * ws;
    }
#pragma unroll
    for (int k = 0; k < 4; ++k) {
        float v = a0[k];
        if (BIAS) v += bias[c0 + k];
        if (RELU) v = fmaxf(v, 0.0f);
        a0[k] = v;
    }
    if (WF)
        *reinterpret_cast<f32x4*>(outF + (size_t)node * ldo + c0) = *reinterpret_cast<f32x4*>(a0);
    if (WB) {
        u16x4 o;
#pragma unroll
        for (int k = 0; k < 4; ++k) o[k] = f2bf(a0[k]);
        *reinterpret_cast<u16x4*>(outB + (size_t)node * ldo + c0) = o;
    }
}

extern "C" void kernel_launch(void* const* d_in, const int* in_sizes, int n_in,
                              void* d_out, int out_size, void* d_ws, size_t ws_size,
                              hipStream_t stream)
{
    const float* x  = (const float*)d_in[0];
    const int* ei1  = (const int*)d_in[1];
    const int* ei2  = (const int*)d_in[2];
    const float* W1 = (const float*)d_in[3];
    const float* b1 = (const float*)d_in[4];
    const float* W2 = (const float*)d_in[5];
    const float* b2 = (const float*)d_in[6];
    const float* W3 = (const float*)d_in[7];
    const float* b3 = (const float*)d_in[8];
    const float* W4 = (const float*)d_in[9];
    const float* b4 = (const float*)d_in[10];
    float* z   = (float*)d_out;                        // [50000,256] f32
    float* z_g = z + (size_t)N_NODES * 256;            // [50000,256] f32

    const int E1 = in_sizes[1] / 2, E2 = in_sizes[2] / 2;
    const int* src1 = ei1;  const int* dst1 = ei1 + E1;
    const int* src2 = ei2;  const int* dst2 = ei2 + E2;

    // ---- aliases on d_out (each half = 51.2 MB = [50000,512] bf16 exactly) ----
    ushort* Xb = (ushort*)z;      // bf16 x; dead after GEMM1; z f32 written later by gather L2
    ushort* R1 = (ushort*)z_g;    // 512-wide bf16 ping buffer; final gather writes z_g f32 over it

    // ---- workspace (~62 MB) ----
    char* ws = (char*)d_ws;
    size_t off = 0;
    auto alloc = [&](size_t bytes) { void* p = ws + off; off += (bytes + 255) & ~(size_t)255; return p; };
    ushort* R0   = (ushort*)alloc((size_t)N_NODES * 512 * 2);
    int*    deg  = (int*)   alloc((size_t)2 * N_NODES * 4);   // [2N]: set1, set2
    float*  inv  = (float*) alloc((size_t)2 * N_NODES * 4);   // [2N]
    int*    pre  = (int*)   alloc((size_t)2 * N_NODES * 4);   // [2N]
    int*    bsum = (int*)   alloc(2 * 256 * 4);
    int*    rp1  = (int*)   alloc((size_t)(N_NODES + 1) * 4);
    int*    rp2  = (int*)   alloc((size_t)(N_NODES + 1) * 4);
    int*    cur1 = (int*)   alloc((size_t)N_NODES * 4);
    int*    cur2 = (int*)   alloc((size_t)N_NODES * 4);
    int2*   adjw1= (int2*)  alloc((size_t)E1 * 8);
    int2*   adjw2= (int2*)  alloc((size_t)E2 * 8);
    ushort* Wt1  = (ushort*)alloc(512 * 512 * 2);
    ushort* Wt2  = (ushort*)alloc(256 * 512 * 2);
    ushort* Wt3  = (ushort*)alloc(512 * 256 * 2);
    ushort* Wt4  = (ushort*)alloc(256 * 512 * 2);
    float*  inv1 = inv;
    float*  inv2 = inv + N_NODES;

    const dim3 blk(256);
    const dim3 gblk(512);
    const int MT = MP / 128;                 // 391 row tiles
    const int GB = (N_NODES + 3) / 4;        // gather blocks (4 waves, 1 node/wave)
    const int NB = (N_NODES + 255) / 256;    // 196 scan blocks

    // ---- CSR build (combined over both edge sets) ----
    hipMemsetAsync(deg, 0, (size_t)2 * N_NODES * 4, stream);
    deg_both_kernel<<<(E1 + E2 + 255) / 256, blk, 0, stream>>>(dst1, E1, dst2, E2, deg);
    inv_both_kernel<<<(2 * N_NODES + 255) / 256, blk, 0, stream>>>(deg, inv);
    scan1_kernel<<<dim3(NB, 2), blk, 0, stream>>>(deg, pre, bsum, N_NODES);
    scan2_kernel<<<2, blk, 0, stream>>>(bsum, NB);
    scan3_kernel<<<dim3(NB, 2), blk, 0, stream>>>(pre, bsum, rp1, cur1, rp2, cur2, N_NODES);
    fill_both_kernel<<<(E1 + E2 + 255) / 256, blk, 0, stream>>>(
        src1, dst1, E1, src2, dst2, E2, inv, cur1, cur2, adjw1, adjw2);
    // rp[N] (total edge count) is never read by gathers: row_ptr[node+1] for node<N-1 comes
    // from rp[0..N-1]; node N-1 uses rp1[N]... so set it via the scan3 trick: write rp[N]=E.
    hipMemsetAsync(rp1 + N_NODES, 0, 4, stream);   // placeholder; fixed below
    hipMemsetAsync(rp2 + N_NODES, 0, 4, stream);

    // ---- weight prep + x -> bf16 ----
    transpose4_kernel<<<(655360 + 255) / 256, blk, 0, stream>>>(W1, Wt1, W2, Wt2, W3, Wt3, W4, Wt4);
    f2b_kernel<<<(N_NODES * 512 / 4 + 255) / 256, blk, 0, stream>>>(x, Xb, N_NODES * 512 / 4);

    // rp[N] = E (single int writes, done with tiny memcpy from host-constant via kernel):
    // use a 1-thread kernel-free approach: hipMemcpyAsync from device adjw? Simplest: small kernel.
    // (inline lambda kernels aren't allowed; use a dedicated 1-block write via scan2-style hack)
    // -- handled by writeE_kernel below --
    {
        static_assert(true, "");
    }
    // write rp1[N]=E1, rp2[N]=E2
    struct W { int* p; int v; };
    // dedicated kernel:
    extern __global__ void writeE_kernel(int* p1, int v1, int* p2, int v2);
    writeE_kernel<<<1, 1, 0, stream>>>(rp1 + N_NODES, E1, rp2 + N_NODES, E2);

    // ---- encoder 1, layer 1: h1 = x@W1 -> R0 ; a1 = relu(P1(h1)+b1) -> R1 ----
    gemm_kernel<<<dim3(4, MT), gblk, 0, stream>>>(Xb, Wt1, R0, nullptr, N_NODES, 512, 512, 0);
    gather512_kernel<<<GB, blk, 0, stream>>>(rp1, adjw1, R0, inv1, b1, R1);

    // ---- encoder 1, layer 2: h2 = a1@W2 -> R0(256) ; z = relu(P1(h2)+b2) -> z f32 + zb -> R1 ----
    gemm_kernel<<<dim3(2, MT), gblk, 0, stream>>>(R1, Wt2, R0, nullptr, N_NODES, 512, 256, 0);
    gather_kernel<true, true, true, true><<<GB, blk, 0, stream>>>(
        rp1, adjw1, R0, 256, inv1, b2, z, R1, 256);

    // ---- encoder 2, layer 1 (propagate-first): pz = P2(zb) -> R0(256) ; a3 = relu(pz@W3+b3) -> R1 ----
    gather_kernel<false, false, false, true><<<GB, blk, 0, stream>>>(
        rp2, adjw2, R1, 256, inv2, nullptr, nullptr, R0, 256);
    gemm_kernel<<<dim3(4, MT), gblk, 0, stream>>>(R0, Wt3, R1, b3, N_NODES, 256, 512, 1);

    // ---- encoder 2, layer 2: h4 = a3@W4 -> R0(256) ; z_g = relu(P2(h4)+b4) -> z_g f32 ----
    gemm_kernel<<<dim3(2, MT), gblk, 0, stream>>>(R1, Wt4, R0, nullptr, N_NODES, 512, 256, 0);
    gather_kernel<true, true, true, false><<<GB, blk, 0, stream>>>(
        rp2, adjw2, R0, 256, inv2, b4, z_g, nullptr, 256);
}

__global__ void writeE_kernel(int* p1, int v1, int* p2, int v2) {
    *p1 = v1; *p2 = v2;
}

// Round 12
// 455.712 us; speedup vs baseline: 1.1042x; 1.0164x over previous
//
#include <hip/hip_runtime.h>

#define N_NODES 50000
#define MP 50048            // row-tile padding (128-multiple) for GEMM grids

typedef short short8 __attribute__((ext_vector_type(8)));
typedef float floatx4 __attribute__((ext_vector_type(4)));
typedef ushort u16x4 __attribute__((ext_vector_type(4)));
typedef ushort u16x8 __attribute__((ext_vector_type(8)));
typedef float f32x4 __attribute__((ext_vector_type(4)));

__device__ __forceinline__ float bf2f(ushort u) {
    union { unsigned int i; float f; } x; x.i = ((unsigned int)u) << 16; return x.f;
}
__device__ __forceinline__ ushort f2bf(float f) {
    union { float f; unsigned int i; } x; x.f = f;
    unsigned int r = x.i + 0x7FFFu + ((x.i >> 16) & 1u);
    return (ushort)(r >> 16);
}

// ---------- combined CSR build (both edge sets in one launch) ----------
__global__ __launch_bounds__(256) void deg_both_kernel(const int* __restrict__ dst1, int E1,
                                                       const int* __restrict__ dst2, int E2,
                                                       int* __restrict__ deg /* [2*N] */) {
    int i = blockIdx.x * 256 + threadIdx.x;
    if (i < E1) atomicAdd(&deg[dst1[i]], 1);
    else if (i - E1 < E2) atomicAdd(&deg[N_NODES + dst2[i - E1]], 1);
}
// stage 1: per-block local exclusive scan + fused inv-sqrt; grid.y selects edge set
__global__ __launch_bounds__(256) void scan1_kernel(const int* __restrict__ deg,
                                                    int* __restrict__ pre,
                                                    int* __restrict__ bsum,
                                                    float* __restrict__ inv, int n) {
    __shared__ int tmp[256];
    const int set = blockIdx.y;
    const int t = threadIdx.x;
    const int i = blockIdx.x * 256 + t;
    const int v = (i < n) ? deg[set * n + i] : 0;
    if (i < n) inv[set * n + i] = rsqrtf((float)v + 1.0f);
    tmp[t] = v;
    __syncthreads();
#pragma unroll
    for (int d = 1; d < 256; d <<= 1) {
        int u = (t >= d) ? tmp[t - d] : 0;
        __syncthreads();
        tmp[t] += u;
        __syncthreads();
    }
    if (i < n) pre[set * n + i] = tmp[t] - v;
    if (t == 255) bsum[set * 256 + blockIdx.x] = tmp[255];
}
// stage 2: blockIdx.x selects edge set; also writes grand total -> rp[N]
__global__ __launch_bounds__(256) void scan2_kernel(int* __restrict__ bsum, int nb,
                                                    int* __restrict__ rpN1,
                                                    int* __restrict__ rpN2) {
    __shared__ int tmp[256];
    const int set = blockIdx.x;
    bsum += set * 256;
    const int t = threadIdx.x;
    const int v = (t < nb) ? bsum[t] : 0;
    tmp[t] = v;
    __syncthreads();
#pragma unroll
    for (int d = 1; d < 256; d <<= 1) {
        int u = (t >= d) ? tmp[t - d] : 0;
        __syncthreads();
        tmp[t] += u;
        __syncthreads();
    }
    if (t < nb) bsum[t] = tmp[t] - v;
    if (t == 255) *(set ? rpN2 : rpN1) = tmp[255];    // grand total = E
}
// stage 3: add block offset -> row_ptr + cursor; grid.y selects edge set
__global__ __launch_bounds__(256) void scan3_kernel(const int* __restrict__ pre,
                                                    const int* __restrict__ bsum,
                                                    int* __restrict__ rp1, int* __restrict__ cur1,
                                                    int* __restrict__ rp2, int* __restrict__ cur2,
                                                    int n) {
    const int set = blockIdx.y;
    int* rp  = set ? rp2 : rp1;
    int* cur = set ? cur2 : cur1;
    const int i = blockIdx.x * 256 + threadIdx.x;
    if (i < n) {
        int v = pre[set * n + i] + bsum[set * 256 + blockIdx.x];
        rp[i] = v;
        cur[i] = v;
    }
}
// fill both adjacency arrays: adjw[pos] = (src, bits(invs[src]))
__global__ __launch_bounds__(256) void fill_both_kernel(
    const int* __restrict__ src1, const int* __restrict__ dst1, int E1,
    const int* __restrict__ src2, const int* __restrict__ dst2, int E2,
    const float* __restrict__ inv /* [2*N] */,
    int* __restrict__ cur1, int* __restrict__ cur2,
    int2* __restrict__ adjw1, int2* __restrict__ adjw2) {
    int i = blockIdx.x * 256 + threadIdx.x;
    if (i < E1) {
        int s = src1[i];
        int pos = atomicAdd(&cur1[dst1[i]], 1);
        adjw1[pos] = make_int2(s, __float_as_int(inv[s]));
    } else if (i - E1 < E2) {
        int j = i - E1;
        int s = src2[j];
        int pos = atomicAdd(&cur2[dst2[j]], 1);
        adjw2[pos] = make_int2(s, __float_as_int(inv[N_NODES + s]));
    }
}

// ---------- combined prep: 4 weight transposes (f32->bf16) + x->bf16 (4 elem/thread) ----------
#define T4_TOTAL 655360              // 262144 + 131072 + 131072 + 131072
__global__ __launch_bounds__(256) void prep_convert_kernel(
    const float* __restrict__ W1, ushort* __restrict__ Wt1,
    const float* __restrict__ W2, ushort* __restrict__ Wt2,
    const float* __restrict__ W3, ushort* __restrict__ Wt3,
    const float* __restrict__ W4, ushort* __restrict__ Wt4,
    const float* __restrict__ x, ushort* __restrict__ Xb, int n4) {
    int idx = blockIdx.x * 256 + threadIdx.x;
    if (idx < T4_TOTAL) {
        const float* W; ushort* Wt; int K, N;
        if (idx < 262144)      { W = W1; Wt = Wt1; K = 512; N = 512; }
        else if (idx < 393216) { W = W2; Wt = Wt2; K = 512; N = 256; idx -= 262144; }
        else if (idx < 524288) { W = W3; Wt = Wt3; K = 256; N = 512; idx -= 393216; }
        else                   { W = W4; Wt = Wt4; K = 512; N = 256; idx -= 524288; }
        int k = idx / N, n = idx % N;
        Wt[n * K + k] = f2bf(W[idx]);
    } else {
        int i = idx - T4_TOTAL;
        if (i < n4) {
            const f32x4 v = *reinterpret_cast<const f32x4*>(x + (size_t)i * 4);
            u16x4 o;
#pragma unroll
            for (int k = 0; k < 4; ++k) o[k] = f2bf(v[k]);
            *reinterpret_cast<u16x4*>(Xb + (size_t)i * 4) = o;
        }
    }
}

// ---------- bf16 MFMA GEMM:  C[M,N] = A[M,K] @ Bt[N,K]^T ----------
// 128x128 tile, 8 waves (512 thr), wave = 64x32 quadrant -> 32 AGPR acc.
__global__ __launch_bounds__(512, 4) void gemm_kernel(
    const ushort* __restrict__ A, const ushort* __restrict__ Bt,
    ushort* __restrict__ C, const float* __restrict__ bias,
    int M, int K, int N, int do_relu)
{
    __shared__ __align__(16) ushort Alds[128 * 32];
    __shared__ __align__(16) ushort Blds[128 * 32];
    const int t = threadIdx.x;
    const int w = t >> 6, l = t & 63;
    const int m0 = blockIdx.y * 128;
    const int n0 = blockIdx.x * 128;
    const int wr = (w >> 2) * 64, wc = (w & 3) * 32;
    const int lhi = l >> 4, llo = l & 15;

    floatx4 acc[4][2] = {};

    const int srow = w * 16 + (l >> 2);      // 0..127
    const int scol = (l & 3) * 8;            // ushort offset within row
    int gr = m0 + srow; gr = gr < M ? gr : M - 1;
    const ushort* gA = A + (size_t)gr * K + scol;
    const ushort* gB = Bt + (size_t)(n0 + srow) * K + scol;
    ushort* lA = Alds + srow * 32 + scol;
    ushort* lB = Blds + srow * 32 + scol;

    const int nkt = K >> 5;
    for (int kt = 0; kt < nkt; ++kt) {
        const int k0 = kt << 5;
        __builtin_amdgcn_global_load_lds(
            (const __attribute__((address_space(1))) void*)(gA + k0),
            (__attribute__((address_space(3))) void*)lA, 16, 0, 0);
        __builtin_amdgcn_global_load_lds(
            (const __attribute__((address_space(1))) void*)(gB + k0),
            (__attribute__((address_space(3))) void*)lB, 16, 0, 0);
        __syncthreads();
        short8 av[4], bv[2];
#pragma unroll
        for (int m = 0; m < 4; ++m)
            av[m] = *reinterpret_cast<const short8*>(&Alds[(wr + m * 16 + llo) * 32 + lhi * 8]);
#pragma unroll
        for (int n = 0; n < 2; ++n)
            bv[n] = *reinterpret_cast<const short8*>(&Blds[(wc + n * 16 + llo) * 32 + lhi * 8]);
#pragma unroll
        for (int m = 0; m < 4; ++m)
#pragma unroll
            for (int n = 0; n < 2; ++n)
                acc[m][n] = __builtin_amdgcn_mfma_f32_16x16x32_bf16(av[m], bv[n], acc[m][n], 0, 0, 0);
        __syncthreads();
    }

    const int lr = lhi * 4;
#pragma unroll
    for (int m = 0; m < 4; ++m) {
#pragma unroll
        for (int n = 0; n < 2; ++n) {
            int gcol = n0 + wc + n * 16 + llo;
            float badd = bias ? bias[gcol] : 0.0f;
#pragma unroll
            for (int j = 0; j < 4; ++j) {
                int grow = m0 + wr + m * 16 + lr + j;
                if (grow < M) {
                    float v = acc[m][n][j] + badd;
                    if (do_relu) v = fmaxf(v, 0.0f);
                    C[(size_t)grow * N + gcol] = f2bf(v);
                }
            }
        }
    }
}

// ---------- 512-wide CSR gather (layer 1): one node/wave, lane owns 8 of 512 ch ----------
__global__ __launch_bounds__(256) void gather512_kernel(
    const int* __restrict__ row_ptr, const int2* __restrict__ adjw,
    const ushort* __restrict__ h, const float* __restrict__ invs,
    const float* __restrict__ bias, ushort* __restrict__ outB)
{
    const int wv = threadIdx.x >> 6, l = threadIdx.x & 63;
    const int node = blockIdx.x * 4 + wv;
    if (node >= N_NODES) return;
    const int c0 = l * 8;
    const int beg = row_ptr[node], end = row_ptr[node + 1];
    const float invd = invs[node];

    float a0[8] = {}, a1[8] = {}, a2[8] = {}, a3[8] = {};
    int e = beg;
    for (; e + 4 <= end; e += 4) {
        const int2 w0 = adjw[e], w1 = adjw[e+1], w2 = adjw[e+2], w3 = adjw[e+3];
        const float f0 = __int_as_float(w0.y) * invd, f1 = __int_as_float(w1.y) * invd;
        const float f2 = __int_as_float(w2.y) * invd, f3 = __int_as_float(w3.y) * invd;
        const u16x8 h0 = *reinterpret_cast<const u16x8*>(h + (unsigned)(w0.x * 512 + c0));
        const u16x8 h1 = *reinterpret_cast<const u16x8*>(h + (unsigned)(w1.x * 512 + c0));
        const u16x8 h2 = *reinterpret_cast<const u16x8*>(h + (unsigned)(w2.x * 512 + c0));
        const u16x8 h3 = *reinterpret_cast<const u16x8*>(h + (unsigned)(w3.x * 512 + c0));
#pragma unroll
        for (int k = 0; k < 8; ++k) {
            a0[k] += bf2f(h0[k]) * f0;
            a1[k] += bf2f(h1[k]) * f1;
            a2[k] += bf2f(h2[k]) * f2;
            a3[k] += bf2f(h3[k]) * f3;
        }
    }
    if (e + 2 <= end) {
        const int2 w0 = adjw[e], w1 = adjw[e+1];
        const float f0 = __int_as_float(w0.y) * invd, f1 = __int_as_float(w1.y) * invd;
        const u16x8 h0 = *reinterpret_cast<const u16x8*>(h + (unsigned)(w0.x * 512 + c0));
        const u16x8 h1 = *reinterpret_cast<const u16x8*>(h + (unsigned)(w1.x * 512 + c0));
#pragma unroll
        for (int k = 0; k < 8; ++k) {
            a0[k] += bf2f(h0[k]) * f0;
            a1[k] += bf2f(h1[k]) * f1;
        }
        e += 2;
    }
    if (e < end) {
        const int2 w0 = adjw[e];
        const float f0 = __int_as_float(w0.y) * invd;
        const u16x8 h0 = *reinterpret_cast<const u16x8*>(h + (unsigned)(w0.x * 512 + c0));
#pragma unroll
        for (int k = 0; k < 8; ++k) a0[k] += bf2f(h0[k]) * f0;
    }
    {
        const float ws = invd * invd;
        const u16x8 hs = *reinterpret_cast<const u16x8*>(h + (unsigned)(node * 512 + c0));
#pragma unroll
        for (int k = 0; k < 8; ++k)
            a0[k] = (a0[k] + a1[k]) + (a2[k] + a3[k]) + bf2f(hs[k]) * ws;
    }
    u16x8 o;
#pragma unroll
    for (int k = 0; k < 8; ++k)
        o[k] = f2bf(fmaxf(a0[k] + bias[c0 + k], 0.0f));
    *reinterpret_cast<u16x8*>(outB + (size_t)node * 512 + c0) = o;
}

// ---------- 256-wide CSR gather + fused epilogue ----------
template<bool RELU, bool BIAS, bool WF, bool WB>
__global__ __launch_bounds__(256) void gather_kernel(
    const int* __restrict__ row_ptr, const int2* __restrict__ adjw,
    const ushort* __restrict__ h, int ldh,
    const float* __restrict__ invs, const float* __restrict__ bias,
    float* __restrict__ outF, ushort* __restrict__ outB, int ldo)
{
    const int wv = threadIdx.x >> 6, l = threadIdx.x & 63;
    const int node = blockIdx.x * 4 + wv;
    if (node >= N_NODES) return;
    const int c0 = l * 4;
    const int beg = row_ptr[node], end = row_ptr[node + 1];
    const float invd = invs[node];

    float a0[4] = {}, a1[4] = {}, a2[4] = {}, a3[4] = {};
    int e = beg;
    for (; e + 4 <= end; e += 4) {
        const int2 w0 = adjw[e], w1 = adjw[e+1], w2 = adjw[e+2], w3 = adjw[e+3];
        const float f0 = __int_as_float(w0.y) * invd, f1 = __int_as_float(w1.y) * invd;
        const float f2 = __int_as_float(w2.y) * invd, f3 = __int_as_float(w3.y) * invd;
        const u16x4 h0 = *reinterpret_cast<const u16x4*>(h + (unsigned)(w0.x * ldh + c0));
        const u16x4 h1 = *reinterpret_cast<const u16x4*>(h + (unsigned)(w1.x * ldh + c0));
        const u16x4 h2 = *reinterpret_cast<const u16x4*>(h + (unsigned)(w2.x * ldh + c0));
        const u16x4 h3 = *reinterpret_cast<const u16x4*>(h + (unsigned)(w3.x * ldh + c0));
#pragma unroll
        for (int k = 0; k < 4; ++k) {
            a0[k] += bf2f(h0[k]) * f0;
            a1[k] += bf2f(h1[k]) * f1;
            a2[k] += bf2f(h2[k]) * f2;
            a3[k] += bf2f(h3[k]) * f3;
        }
    }
    if (e + 2 <= end) {
        const int2 w0 = adjw[e], w1 = adjw[e+1];
        const float f0 = __int_as_float(w0.y) * invd, f1 = __int_as_float(w1.y) * invd;
        const u16x4 h0 = *reinterpret_cast<const u16x4*>(h + (unsigned)(w0.x * ldh + c0));
        const u16x4 h1 = *reinterpret_cast<const u16x4*>(h + (unsigned)(w1.x * ldh + c0));
#pragma unroll
        for (int k = 0; k < 4; ++k) {
            a0[k] += bf2f(h0[k]) * f0;
            a1[k] += bf2f(h1[k]) * f1;
        }
        e += 2;
    }
    if (e < end) {
        const int2 w0 = adjw[e];
        const float f0 = __int_as_float(w0.y) * invd;
        const u16x4 h0 = *reinterpret_cast<const u16x4*>(h + (unsigned)(w0.x * ldh + c0));
#pragma unroll
        for (int k = 0; k < 4; ++k) a0[k] += bf2f(h0[k]) * f0;
    }
    {
        const float ws = invd * invd;
        const u16x4 hs = *reinterpret_cast<const u16x4*>(h + (unsigned)(node * ldh + c0));
#pragma unroll
        for (int k = 0; k < 4; ++k)
            a0[k] = (a0[k] + a1[k]) + (a2[k] + a3[k]) + bf2f(hs[k]) * ws;
    }
#pragma unroll
    for (int k = 0; k < 4; ++k) {
        float v = a0[k];
        if (BIAS) v += bias[c0 + k];
        if (RELU) v = fmaxf(v, 0.0f);
        a0[k] = v;
    }
    if (WF)
        *reinterpret_cast<f32x4*>(outF + (size_t)node * ldo + c0) = *reinterpret_cast<f32x4*>(a0);
    if (WB) {
        u16x4 o;
#pragma unroll
        for (int k = 0; k < 4; ++k) o[k] = f2bf(a0[k]);
        *reinterpret_cast<u16x4*>(outB + (size_t)node * ldo + c0) = o;
    }
}

extern "C" void kernel_launch(void* const* d_in, const int* in_sizes, int n_in,
                              void* d_out, int out_size, void* d_ws, size_t ws_size,
                              hipStream_t stream)
{
    const float* x  = (const float*)d_in[0];
    const int* ei1  = (const int*)d_in[1];
    const int* ei2  = (const int*)d_in[2];
    const float* W1 = (const float*)d_in[3];
    const float* b1 = (const float*)d_in[4];
    const float* W2 = (const float*)d_in[5];
    const float* b2 = (const float*)d_in[6];
    const float* W3 = (const float*)d_in[7];
    const float* b3 = (const float*)d_in[8];
    const float* W4 = (const float*)d_in[9];
    const float* b4 = (const float*)d_in[10];
    float* z   = (float*)d_out;                        // [50000,256] f32
    float* z_g = z + (size_t)N_NODES * 256;            // [50000,256] f32

    const int E1 = in_sizes[1] / 2, E2 = in_sizes[2] / 2;
    const int* src1 = ei1;  const int* dst1 = ei1 + E1;
    const int* src2 = ei2;  const int* dst2 = ei2 + E2;

    // ---- aliases on d_out (each half = 51.2 MB = [50000,512] bf16 exactly) ----
    ushort* Xb = (ushort*)z;      // bf16 x; dead after GEMM1; z f32 written later by gather L2
    ushort* R1 = (ushort*)z_g;    // 512-wide bf16 ping buffer; final gather writes z_g f32 over it

    // ---- workspace (~62 MB) ----
    char* ws = (char*)d_ws;
    size_t off = 0;
    auto alloc = [&](size_t bytes) { void* p = ws + off; off += (bytes + 255) & ~(size_t)255; return p; };
    ushort* R0   = (ushort*)alloc((size_t)N_NODES * 512 * 2);
    int*    deg  = (int*)   alloc((size_t)2 * N_NODES * 4);   // [2N]: set1, set2
    float*  inv  = (float*) alloc((size_t)2 * N_NODES * 4);   // [2N]
    int*    pre  = (int*)   alloc((size_t)2 * N_NODES * 4);   // [2N]
    int*    bsum = (int*)   alloc(2 * 256 * 4);
    int*    rp1  = (int*)   alloc((size_t)(N_NODES + 1) * 4);
    int*    rp2  = (int*)   alloc((size_t)(N_NODES + 1) * 4);
    int*    cur1 = (int*)   alloc((size_t)N_NODES * 4);
    int*    cur2 = (int*)   alloc((size_t)N_NODES * 4);
    int2*   adjw1= (int2*)  alloc((size_t)E1 * 8);
    int2*   adjw2= (int2*)  alloc((size_t)E2 * 8);
    ushort* Wt1  = (ushort*)alloc(512 * 512 * 2);
    ushort* Wt2  = (ushort*)alloc(256 * 512 * 2);
    ushort* Wt3  = (ushort*)alloc(512 * 256 * 2);
    ushort* Wt4  = (ushort*)alloc(256 * 512 * 2);
    float*  inv1 = inv;
    float*  inv2 = inv + N_NODES;

    const dim3 blk(256);
    const dim3 gblk(512);
    const int MT = MP / 128;                 // 391 row tiles
    const int GB = (N_NODES + 3) / 4;        // gather blocks (4 waves, 1 node/wave)
    const int NB = (N_NODES + 255) / 256;    // 196 scan blocks

    // ---- CSR build (combined over both edge sets) ----
    hipMemsetAsync(deg, 0, (size_t)2 * N_NODES * 4, stream);
    deg_both_kernel<<<(E1 + E2 + 255) / 256, blk, 0, stream>>>(dst1, E1, dst2, E2, deg);
    scan1_kernel<<<dim3(NB, 2), blk, 0, stream>>>(deg, pre, bsum, inv, N_NODES);
    scan2_kernel<<<2, blk, 0, stream>>>(bsum, NB, rp1 + N_NODES, rp2 + N_NODES);
    scan3_kernel<<<dim3(NB, 2), blk, 0, stream>>>(pre, bsum, rp1, cur1, rp2, cur2, N_NODES);
    fill_both_kernel<<<(E1 + E2 + 255) / 256, blk, 0, stream>>>(
        src1, dst1, E1, src2, dst2, E2, inv, cur1, cur2, adjw1, adjw2);

    // ---- weight prep + x -> bf16 (one kernel) ----
    const int n4 = N_NODES * 512 / 4;
    prep_convert_kernel<<<(T4_TOTAL + n4 + 255) / 256, blk, 0, stream>>>(
        W1, Wt1, W2, Wt2, W3, Wt3, W4, Wt4, x, Xb, n4);

    // ---- encoder 1, layer 1: h1 = x@W1 -> R0 ; a1 = relu(P1(h1)+b1) -> R1 ----
    gemm_kernel<<<dim3(4, MT), gblk, 0, stream>>>(Xb, Wt1, R0, nullptr, N_NODES, 512, 512, 0);
    gather512_kernel<<<GB, blk, 0, stream>>>(rp1, adjw1, R0, inv1, b1, R1);

    // ---- encoder 1, layer 2: h2 = a1@W2 -> R0(256) ; z = relu(P1(h2)+b2) -> z f32 + zb -> R1 ----
    gemm_kernel<<<dim3(2, MT), gblk, 0, stream>>>(R1, Wt2, R0, nullptr, N_NODES, 512, 256, 0);
    gather_kernel<true, true, true, true><<<GB, blk, 0, stream>>>(
        rp1, adjw1, R0, 256, inv1, b2, z, R1, 256);

    // ---- encoder 2, layer 1 (propagate-first): pz = P2(zb) -> R0(256) ; a3 = relu(pz@W3+b3) -> R1 ----
    gather_kernel<false, false, false, true><<<GB, blk, 0, stream>>>(
        rp2, adjw2, R1, 256, inv2, nullptr, nullptr, R0, 256);
    gemm_kernel<<<dim3(4, MT), gblk, 0, stream>>>(R0, Wt3, R1, b3, N_NODES, 256, 512, 1);

    // ---- encoder 2, layer 2: h4 = a3@W4 -> R0(256) ; z_g = relu(P2(h4)+b4) -> z_g f32 ----
    gemm_kernel<<<dim3(2, MT), gblk, 0, stream>>>(R1, Wt4, R0, nullptr, N_NODES, 512, 256, 0);
    gather_kernel<true, true, true, false><<<GB, blk, 0, stream>>>(
        rp2, adjw2, R0, 256, inv2, b4, z_g, nullptr, 256);
}